// Round 1
// baseline (228.523 us; speedup 1.0000x reference)
//
#include <hip/hip_runtime.h>

typedef __bf16 bf16_t;
typedef __bf16 bf16x8 __attribute__((ext_vector_type(8)));
typedef __bf16 bf16x4 __attribute__((ext_vector_type(4)));
typedef float f32x4 __attribute__((ext_vector_type(4)));

#define M_DIM 4096
#define N_DIM 4096  // 2 * OUT_FEATURES
#define K_DIM 4096  // 2 * IN_FEATURES
#define OUTF 2048
#define INF 2048

// ---------------------------------------------------------------------------
// Pack kernel: build bf16 A = [x_re | x_im]  (4096 x 4096)
//              and  bf16 B = [[w_re, -w_im]; [w_im, w_re]] (4096 x 4096)
// ---------------------------------------------------------------------------
__global__ __launch_bounds__(256) void pack_ab(
    const float* __restrict__ xre, const float* __restrict__ xim,
    const float* __restrict__ wre, const float* __restrict__ wim,
    bf16_t* __restrict__ Abf, bf16_t* __restrict__ Bbf)
{
  size_t gid = (size_t)blockIdx.x * 256 + threadIdx.x;
  size_t e8  = gid * 8;                      // element index in [0, 2*4096*4096)
  const size_t MAT = (size_t)4096 * 4096;
  bool isB = e8 >= MAT;
  size_t e = isB ? (e8 - MAT) : e8;
  int row = (int)(e >> 12);                  // /4096
  int k   = (int)(e & 4095);

  const float* src;
  float s = 1.0f;
  if (!isB) {
    src = (k < INF) ? (xre + (size_t)row * INF + k)
                    : (xim + (size_t)row * INF + (k - INF));
  } else {
    if (row < OUTF) {
      if (k < INF) { src = wre + (size_t)row * INF + k; }
      else         { src = wim + (size_t)row * INF + (k - INF); s = -1.0f; }
    } else {
      int o = row - OUTF;
      src = (k < INF) ? (wim + (size_t)o * INF + k)
                      : (wre + (size_t)o * INF + (k - INF));
    }
  }
  const float4* p = reinterpret_cast<const float4*>(src);
  float4 f0 = p[0];
  float4 f1 = p[1];
  bf16x8 v;
  v[0] = (bf16_t)(f0.x * s); v[1] = (bf16_t)(f0.y * s);
  v[2] = (bf16_t)(f0.z * s); v[3] = (bf16_t)(f0.w * s);
  v[4] = (bf16_t)(f1.x * s); v[5] = (bf16_t)(f1.y * s);
  v[6] = (bf16_t)(f1.z * s); v[7] = (bf16_t)(f1.w * s);
  bf16_t* dst = (isB ? Bbf : Abf) + e;
  *reinterpret_cast<bf16x8*>(dst) = v;
}

// ---------------------------------------------------------------------------
// global -> LDS direct copy, 16B per lane
// ---------------------------------------------------------------------------
__device__ __forceinline__ void gld_lds16(const void* g, void* l) {
  __builtin_amdgcn_global_load_lds(
      (const __attribute__((address_space(1))) void*)g,
      (__attribute__((address_space(3))) void*)l,
      16, 0, 0);
}

// ---------------------------------------------------------------------------
// GEMM (packed bf16 operands in ws): m97-style 128x128 tile, BK=32, 4 waves
// C[b][n]: n<2048 -> out_re, else out_im
// ---------------------------------------------------------------------------
__global__ __launch_bounds__(256) void gemm_packed(
    const bf16_t* __restrict__ A, const bf16_t* __restrict__ B,
    float* __restrict__ out)
{
  __shared__ alignas(16) bf16_t As[128 * 32];
  __shared__ alignas(16) bf16_t Bs[128 * 32];

  int tid = threadIdx.x;
  int bid = blockIdx.x;
  // XCD-aware swizzle: 1024 blocks, 8 XCDs -> contiguous chunks of 128
  int swz = (bid & 7) * 128 + (bid >> 3);
  int bm = swz >> 5;   // 0..31
  int bn = swz & 31;   // 0..31

  int lane = tid & 63;
  int w    = tid >> 6;         // wave 0..3
  int wm   = (w >> 1) * 64;    // wave row offset in tile
  int wn   = (w & 1) * 64;     // wave col offset in tile
  int lr   = lane & 15;
  int lk   = (lane >> 4) * 8;

  f32x4 acc[4][4];
#pragma unroll
  for (int m = 0; m < 4; ++m)
#pragma unroll
    for (int n = 0; n < 4; ++n)
      acc[m][n] = (f32x4){0.f, 0.f, 0.f, 0.f};

  int srow = tid >> 2;          // 0..63
  int scol = (tid & 3) * 8;     // k-element offset (8 bf16 = 16B)
  const size_t ldk = K_DIM;

  const bf16_t* Ab = A + (size_t)(bm * 128) * ldk;
  const bf16_t* Bb = B + (size_t)(bn * 128) * ldk;

  for (int kt = 0; kt < K_DIM / 32; ++kt) {
    int k0 = kt * 32;
    gld_lds16(Ab + (size_t)srow * ldk + k0 + scol,        &As[srow * 32 + scol]);
    gld_lds16(Ab + (size_t)(srow + 64) * ldk + k0 + scol, &As[(srow + 64) * 32 + scol]);
    gld_lds16(Bb + (size_t)srow * ldk + k0 + scol,        &Bs[srow * 32 + scol]);
    gld_lds16(Bb + (size_t)(srow + 64) * ldk + k0 + scol, &Bs[(srow + 64) * 32 + scol]);
    __syncthreads();   // drains vmcnt -> tile resident

    bf16x8 a[4], b[4];
#pragma unroll
    for (int m = 0; m < 4; ++m)
      a[m] = *reinterpret_cast<const bf16x8*>(&As[(wm + m * 16 + lr) * 32 + lk]);
#pragma unroll
    for (int n = 0; n < 4; ++n)
      b[n] = *reinterpret_cast<const bf16x8*>(&Bs[(wn + n * 16 + lr) * 32 + lk]);
#pragma unroll
    for (int m = 0; m < 4; ++m)
#pragma unroll
      for (int n = 0; n < 4; ++n)
        acc[m][n] = __builtin_amdgcn_mfma_f32_16x16x32_bf16(a[m], b[n], acc[m][n], 0, 0, 0);
    __syncthreads();   // reads done before next stage overwrites
  }

  // epilogue: C/D layout col=lane&15, row=(lane>>4)*4+j (verified m89/m91)
  const size_t imOff = (size_t)M_DIM * OUTF;
  int fq = (lane >> 4) * 4;
#pragma unroll
  for (int m = 0; m < 4; ++m) {
    int gr = bm * 128 + wm + m * 16 + fq;     // batch row
#pragma unroll
    for (int n = 0; n < 4; ++n) {
      int gc = bn * 128 + wn + n * 16 + lr;   // col in [0,4096)
      float* dst = (gc < OUTF) ? (out + (size_t)gr * OUTF + gc)
                               : (out + imOff + (size_t)gr * OUTF + (gc - OUTF));
#pragma unroll
      for (int j = 0; j < 4; ++j)
        dst[(size_t)j * OUTF] = acc[m][n][j];
    }
  }
}

// ---------------------------------------------------------------------------
// Fallback: fused fp32->bf16 conversion + GEMM (no workspace needed).
// Reg-staged LDS with +8 pad ([128][40]) -> 2-way banks on b128 reads (free).
// ---------------------------------------------------------------------------
__global__ __launch_bounds__(256) void gemm_fused(
    const float* __restrict__ xre, const float* __restrict__ xim,
    const float* __restrict__ wre, const float* __restrict__ wim,
    float* __restrict__ out)
{
  __shared__ alignas(16) bf16_t As[128 * 40];
  __shared__ alignas(16) bf16_t Bs[128 * 40];

  int tid = threadIdx.x;
  int bid = blockIdx.x;
  int swz = (bid & 7) * 128 + (bid >> 3);
  int bm = swz >> 5;
  int bn = swz & 31;

  int lane = tid & 63;
  int w    = tid >> 6;
  int wm   = (w >> 1) * 64;
  int wn   = (w & 1) * 64;
  int lr   = lane & 15;
  int lk   = (lane >> 4) * 8;

  f32x4 acc[4][4];
#pragma unroll
  for (int m = 0; m < 4; ++m)
#pragma unroll
    for (int n = 0; n < 4; ++n)
      acc[m][n] = (f32x4){0.f, 0.f, 0.f, 0.f};

  int srow = tid >> 3;        // 0..31
  int scol = (tid & 7) * 4;   // float4 offset within BK=32

  bool nIm  = (bn * 128) >= OUTF;          // block-uniform (128 | 2048)
  int nbase = nIm ? (bn * 128 - OUTF) : (bn * 128);

  for (int kt = 0; kt < K_DIM / 32; ++kt) {
    int k0 = kt * 32;
    bool kHi = (k0 >= INF);                // tile-uniform (32 | 2048)
    int kk = kHi ? (k0 - INF) : k0;

    const float* Asrc = (kHi ? xim : xre) + (size_t)(bm * 128) * INF + kk;
    const float* Bsrc;
    float s = 1.0f;
    if (!nIm) { if (!kHi) { Bsrc = wre; } else { Bsrc = wim; s = -1.0f; } }
    else      { Bsrc = kHi ? wre : wim; }
    Bsrc += (size_t)nbase * INF + kk;

    float4 av[4], bv[4];
#pragma unroll
    for (int i = 0; i < 4; ++i) {
      av[i] = *reinterpret_cast<const float4*>(Asrc + (size_t)(srow + i * 32) * INF + scol);
      bv[i] = *reinterpret_cast<const float4*>(Bsrc + (size_t)(srow + i * 32) * INF + scol);
    }
    __syncthreads();   // previous iteration's ds_reads complete
#pragma unroll
    for (int i = 0; i < 4; ++i) {
      bf16x4 a4, b4;
      a4[0] = (bf16_t)av[i].x; a4[1] = (bf16_t)av[i].y;
      a4[2] = (bf16_t)av[i].z; a4[3] = (bf16_t)av[i].w;
      b4[0] = (bf16_t)(bv[i].x * s); b4[1] = (bf16_t)(bv[i].y * s);
      b4[2] = (bf16_t)(bv[i].z * s); b4[3] = (bf16_t)(bv[i].w * s);
      *reinterpret_cast<bf16x4*>(&As[(srow + i * 32) * 40 + scol]) = a4;
      *reinterpret_cast<bf16x4*>(&Bs[(srow + i * 32) * 40 + scol]) = b4;
    }
    __syncthreads();

    bf16x8 a[4], b[4];
#pragma unroll
    for (int m = 0; m < 4; ++m)
      a[m] = *reinterpret_cast<const bf16x8*>(&As[(wm + m * 16 + lr) * 40 + lk]);
#pragma unroll
    for (int n = 0; n < 4; ++n)
      b[n] = *reinterpret_cast<const bf16x8*>(&Bs[(wn + n * 16 + lr) * 40 + lk]);
#pragma unroll
    for (int m = 0; m < 4; ++m)
#pragma unroll
      for (int n = 0; n < 4; ++n)
        acc[m][n] = __builtin_amdgcn_mfma_f32_16x16x32_bf16(a[m], b[n], acc[m][n], 0, 0, 0);
  }
  __syncthreads();

  const size_t imOff = (size_t)M_DIM * OUTF;
  int fq = (lane >> 4) * 4;
#pragma unroll
  for (int m = 0; m < 4; ++m) {
    int gr = bm * 128 + wm + m * 16 + fq;
#pragma unroll
    for (int n = 0; n < 4; ++n) {
      int gc = bn * 128 + wn + n * 16 + lr;
      float* dst = (gc < OUTF) ? (out + (size_t)gr * OUTF + gc)
                               : (out + imOff + (size_t)gr * OUTF + (gc - OUTF));
#pragma unroll
      for (int j = 0; j < 4; ++j)
        dst[(size_t)j * OUTF] = acc[m][n][j];
    }
  }
}

// ---------------------------------------------------------------------------
extern "C" void kernel_launch(void* const* d_in, const int* in_sizes, int n_in,
                              void* d_out, int out_size, void* d_ws, size_t ws_size,
                              hipStream_t stream) {
  const float* xre = (const float*)d_in[0];
  const float* xim = (const float*)d_in[1];
  const float* wre = (const float*)d_in[2];
  const float* wim = (const float*)d_in[3];
  float* out = (float*)d_out;

  const size_t need = (size_t)2 * 4096 * 4096 * sizeof(bf16_t);  // 64 MiB
  if (ws_size >= need) {
    bf16_t* Abf = (bf16_t*)d_ws;
    bf16_t* Bbf = Abf + (size_t)4096 * 4096;
    hipLaunchKernelGGL(pack_ab, dim3(16384), dim3(256), 0, stream,
                       xre, xim, wre, wim, Abf, Bbf);
    hipLaunchKernelGGL(gemm_packed, dim3(1024), dim3(256), 0, stream,
                       Abf, Bbf, out);
  } else {
    hipLaunchKernelGGL(gemm_fused, dim3(1024), dim3(256), 0, stream,
                       xre, xim, wre, wim, out);
  }
}

// Round 2
// 149.572 us; speedup vs baseline: 1.5278x; 1.5278x over previous
//
#include <hip/hip_runtime.h>

typedef __bf16 bf16_t;
typedef __bf16 bf16x8 __attribute__((ext_vector_type(8)));
typedef __bf16 bf16x4 __attribute__((ext_vector_type(4)));
typedef float f32x4 __attribute__((ext_vector_type(4)));

#define M_DIM 4096
#define N_DIM 4096   // 2 * OUT_FEATURES
#define K_DIM 4096   // 2 * IN_FEATURES
#define OUTF 2048
#define INF 2048
#define LDK 4096
#define NT 64        // K-tiles of 64

// ---------------------------------------------------------------------------
// Pack kernel: build bf16 A = [x_re | x_im]  (4096 x 4096)
//              and  bf16 B = [[w_re, -w_im]; [w_im, w_re]] (4096 x 4096)
// ---------------------------------------------------------------------------
__global__ __launch_bounds__(256) void pack_ab(
    const float* __restrict__ xre, const float* __restrict__ xim,
    const float* __restrict__ wre, const float* __restrict__ wim,
    bf16_t* __restrict__ Abf, bf16_t* __restrict__ Bbf)
{
  size_t gid = (size_t)blockIdx.x * 256 + threadIdx.x;
  size_t e8  = gid * 8;
  const size_t MAT = (size_t)4096 * 4096;
  bool isB = e8 >= MAT;
  size_t e = isB ? (e8 - MAT) : e8;
  int row = (int)(e >> 12);
  int k   = (int)(e & 4095);

  const float* src;
  float s = 1.0f;
  if (!isB) {
    src = (k < INF) ? (xre + (size_t)row * INF + k)
                    : (xim + (size_t)row * INF + (k - INF));
  } else {
    if (row < OUTF) {
      if (k < INF) { src = wre + (size_t)row * INF + k; }
      else         { src = wim + (size_t)row * INF + (k - INF); s = -1.0f; }
    } else {
      int o = row - OUTF;
      src = (k < INF) ? (wim + (size_t)o * INF + k)
                      : (wre + (size_t)o * INF + (k - INF));
    }
  }
  const float4* p = reinterpret_cast<const float4*>(src);
  float4 f0 = p[0];
  float4 f1 = p[1];
  bf16x8 v;
  v[0] = (bf16_t)(f0.x * s); v[1] = (bf16_t)(f0.y * s);
  v[2] = (bf16_t)(f0.z * s); v[3] = (bf16_t)(f0.w * s);
  v[4] = (bf16_t)(f1.x * s); v[5] = (bf16_t)(f1.y * s);
  v[6] = (bf16_t)(f1.z * s); v[7] = (bf16_t)(f1.w * s);
  bf16_t* dst = (isB ? Bbf : Abf) + e;
  *reinterpret_cast<bf16x8*>(dst) = v;
}

// ---------------------------------------------------------------------------
__device__ __forceinline__ void gld_lds16(const void* g, void* l) {
  __builtin_amdgcn_global_load_lds(
      (const __attribute__((address_space(1))) void*)g,
      (__attribute__((address_space(3))) void*)l,
      16, 0, 0);
}

// ---------------------------------------------------------------------------
// 256x256 8-phase GEMM (m201 template, plain HIP).
//   8 waves = 512 thr, 2M x 4N; per-wave 128x64 out; BK=64; LDS 128 KiB dbuf.
//   st_16x32 swizzle: phys_kbyte = kbyte ^ (((row>>2)&1)<<5), applied on
//   pre-swizzled global staging source AND on ds_read addresses (rule 21).
//   Counted vmcnt(2) at phase 4 only (1 half-tile in flight across boundary).
// ---------------------------------------------------------------------------

template<int QM, int QN>
__device__ __forceinline__ void mfma_quad(f32x4 (&acc)[8][4],
                                          const bf16x8 (&aF)[4][2],
                                          const bf16x8 (&bF)[2][2]) {
  __builtin_amdgcn_s_setprio(1);
#pragma unroll
  for (int m = 0; m < 4; ++m)
#pragma unroll
    for (int n = 0; n < 2; ++n) {
      f32x4 v = acc[QM * 4 + m][QN * 2 + n];
      v = __builtin_amdgcn_mfma_f32_16x16x32_bf16(aF[m][0], bF[n][0], v, 0, 0, 0);
      v = __builtin_amdgcn_mfma_f32_16x16x32_bf16(aF[m][1], bF[n][1], v, 0, 0, 0);
      acc[QM * 4 + m][QN * 2 + n] = v;
    }
  __builtin_amdgcn_s_setprio(0);
}

__global__ __launch_bounds__(512, 2) void gemm256(
    const bf16_t* __restrict__ A, const bf16_t* __restrict__ B,
    float* __restrict__ out)
{
  // LDS: buf c at c*65536 bytes; within buf: A-half0|A-half1|B-half0|B-half1,
  // each half = 128 rows x 64 cols bf16 = 16384 B.
  __shared__ alignas(16) bf16_t lds[2 * 32768];
  char* Lb = (char*)lds;

  const int tid  = threadIdx.x;
  const int lane = tid & 63;
  const int wid  = tid >> 6;
  const int wm   = wid >> 2;   // 0..1  -> rows wm*128..+127  (A-half wm)
  const int wn   = wid & 3;    // 0..3  -> cols wn*64..+63
  const int lr   = lane & 15;
  // swizzled per-lane k-byte offset for ds_read_b128 frags:
  const int kx   = ((lane >> 4) * 16) ^ (((lr >> 2) & 1) << 5);

  int bid = blockIdx.x;
  int swz = (bid & 7) * 32 + (bid >> 3);   // XCD-aware, 256 blocks % 8 == 0
  const int bm = swz >> 4;                  // 0..15
  const int bn = swz & 15;                  // 0..15

  // Staging source precompute (involution of linear LDS dest):
  // physical P = j*8192 + tid*16 ; logical L = P ^ (((P>>9)&1)<<5)
  int rS[2], kS[2];
#pragma unroll
  for (int j = 0; j < 2; ++j) {
    int P  = j * 8192 + tid * 16;
    int Lg = P ^ (((P >> 9) & 1) << 5);
    rS[j] = Lg >> 7;          // row in half (0..127)
    kS[j] = (Lg & 127) >> 1;  // k element (0..63)
  }
  const bf16_t* As0 = A + (size_t)(bm * 256 + rS[0]) * LDK + kS[0];
  const bf16_t* As1 = A + (size_t)(bm * 256 + rS[1]) * LDK + kS[1];
  const bf16_t* Bs0 = B + (size_t)(bn * 256 + rS[0]) * LDK + kS[0];
  const bf16_t* Bs1 = B + (size_t)(bn * 256 + rS[1]) * LDK + kS[1];
  const int dst16 = tid * 16;

#define STAGE_A(t, h, c) do {                                                  \
    gld_lds16(As0 + (size_t)(h) * 128 * LDK + (t) * 64,                        \
              Lb + (c) * 65536 + (h) * 16384 + dst16);                         \
    gld_lds16(As1 + (size_t)(h) * 128 * LDK + (t) * 64,                        \
              Lb + (c) * 65536 + (h) * 16384 + 8192 + dst16);                  \
  } while (0)
#define STAGE_B(t, h, c) do {                                                  \
    gld_lds16(Bs0 + (size_t)(h) * 128 * LDK + (t) * 64,                        \
              Lb + (c) * 65536 + 32768 + (h) * 16384 + dst16);                 \
    gld_lds16(Bs1 + (size_t)(h) * 128 * LDK + (t) * 64,                        \
              Lb + (c) * 65536 + 32768 + (h) * 16384 + 8192 + dst16);          \
  } while (0)
// A frag read: row-in-half = qm*64+m*16+lr (half = wm), swizzled k via kx
#define RD_A(c, qm, m, ks)                                                     \
  (*(const bf16x8*)(Lb + (c) * 65536 + wm * 16384 +                            \
                    ((qm) * 64 + (m) * 16 + lr) * 128 + (ks) * 64 + kx))
// B frag read: row = wn*64+qn*32+n*16+lr -> half wn>>1, row-in-half rest
#define RD_B(c, qn, n, ks)                                                     \
  (*(const bf16x8*)(Lb + (c) * 65536 + 32768 + (wn >> 1) * 16384 +             \
                    ((wn & 1) * 64 + (qn) * 32 + (n) * 16 + lr) * 128 +        \
                    (ks) * 64 + kx))
#define BAR()    __builtin_amdgcn_s_barrier()
#define LGKM0()  asm volatile("s_waitcnt lgkmcnt(0)" ::: "memory")

  f32x4 acc[8][4];
#pragma unroll
  for (int i = 0; i < 8; ++i)
#pragma unroll
    for (int j = 0; j < 4; ++j)
      acc[i][j] = (f32x4){0.f, 0.f, 0.f, 0.f};

  // Prologue: tile0 fully into buf0; tile1's A-half0 into buf1 (1 HT in flight)
  STAGE_A(0, 0, 0); STAGE_A(0, 1, 0);
  STAGE_B(0, 0, 0); STAGE_B(0, 1, 0);
  STAGE_A(1, 0, 1);
  asm volatile("s_waitcnt vmcnt(2)" ::: "memory");
  BAR();

  for (int t = 0; t < NT; ++t) {
    const int c = t & 1;
    bf16x8 aF[4][2], bF0[2][2], bF1[2][2];

    // ---- P1: quadrant (0,0). reads: A qm0 (8), B qn0 (4). stage t+1 A1.
#pragma unroll
    for (int m = 0; m < 4; ++m) {
      aF[m][0] = RD_A(c, 0, m, 0);
      aF[m][1] = RD_A(c, 0, m, 1);
    }
#pragma unroll
    for (int n = 0; n < 2; ++n) {
      bF0[n][0] = RD_B(c, 0, n, 0);
      bF0[n][1] = RD_B(c, 0, n, 1);
    }
    if (t + 1 < NT) STAGE_A(t + 1, 1, c ^ 1);
    BAR(); LGKM0();
    mfma_quad<0, 0>(acc, aF, bF0);
    BAR();

    // ---- P2: quadrant (0,1). reads: B qn1 (4). stage t+1 B0.
#pragma unroll
    for (int n = 0; n < 2; ++n) {
      bF1[n][0] = RD_B(c, 1, n, 0);
      bF1[n][1] = RD_B(c, 1, n, 1);
    }
    if (t + 1 < NT) STAGE_B(t + 1, 0, c ^ 1);
    BAR(); LGKM0();
    mfma_quad<0, 1>(acc, aF, bF1);
    BAR();

    // ---- P3: quadrant (1,1). reads: A qm1 (8). stage t+1 B1.
#pragma unroll
    for (int m = 0; m < 4; ++m) {
      aF[m][0] = RD_A(c, 1, m, 0);
      aF[m][1] = RD_A(c, 1, m, 1);
    }
    if (t + 1 < NT) STAGE_B(t + 1, 1, c ^ 1);
    BAR(); LGKM0();
    mfma_quad<1, 1>(acc, aF, bF1);
    BAR();

    // ---- P4: quadrant (1,0). no reads. stage t+2 A0 into buf c (safe: all
    // reads of buf c completed by P3's lgkmcnt+barrier). counted vmcnt.
    if (t + 2 < NT) STAGE_A(t + 2, 0, c);
    mfma_quad<1, 0>(acc, aF, bF0);
    if (t + 2 < NT) {
      asm volatile("s_waitcnt vmcnt(2)" ::: "memory");
    } else if (t + 1 < NT) {
      asm volatile("s_waitcnt vmcnt(0)" ::: "memory");
    }
    BAR();
  }

  // Epilogue: C/D layout col=lane&15, row=(lane>>4)*4+j (verified m89/m91)
  const size_t imOff = (size_t)M_DIM * OUTF;
  const int fq = (lane >> 4) * 4;
  const bool isIm = (bn * 256) >= OUTF;          // bn>=8 -> imaginary half
  float* obase = out + (isIm ? imOff : 0);
  const int colBase = bn * 256 - (isIm ? OUTF : 0) + wn * 64;
#pragma unroll
  for (int ar = 0; ar < 8; ++ar) {
    int gr = bm * 256 + wm * 128 + ar * 16 + fq;
#pragma unroll
    for (int cc = 0; cc < 4; ++cc) {
      int gc = colBase + cc * 16 + lr;
#pragma unroll
      for (int j = 0; j < 4; ++j)
        obase[(size_t)(gr + j) * OUTF + gc] = acc[ar][cc][j];
    }
  }
#undef STAGE_A
#undef STAGE_B
#undef RD_A
#undef RD_B
#undef BAR
#undef LGKM0
}

// ---------------------------------------------------------------------------
// Fallback: fused fp32->bf16 conversion + GEMM (no workspace needed).
// ---------------------------------------------------------------------------
__global__ __launch_bounds__(256) void gemm_fused(
    const float* __restrict__ xre, const float* __restrict__ xim,
    const float* __restrict__ wre, const float* __restrict__ wim,
    float* __restrict__ out)
{
  __shared__ alignas(16) bf16_t As[128 * 40];
  __shared__ alignas(16) bf16_t Bs[128 * 40];

  int tid = threadIdx.x;
  int bid = blockIdx.x;
  int swz = (bid & 7) * 128 + (bid >> 3);
  int bm = swz >> 5;
  int bn = swz & 31;

  int lane = tid & 63;
  int w    = tid >> 6;
  int wm   = (w >> 1) * 64;
  int wn   = (w & 1) * 64;
  int lr   = lane & 15;
  int lk   = (lane >> 4) * 8;

  f32x4 acc[4][4];
#pragma unroll
  for (int m = 0; m < 4; ++m)
#pragma unroll
    for (int n = 0; n < 4; ++n)
      acc[m][n] = (f32x4){0.f, 0.f, 0.f, 0.f};

  int srow = tid >> 3;
  int scol = (tid & 7) * 4;

  bool nIm  = (bn * 128) >= OUTF;
  int nbase = nIm ? (bn * 128 - OUTF) : (bn * 128);

  for (int kt = 0; kt < K_DIM / 32; ++kt) {
    int k0 = kt * 32;
    bool kHi = (k0 >= INF);
    int kk = kHi ? (k0 - INF) : k0;

    const float* Asrc = (kHi ? xim : xre) + (size_t)(bm * 128) * INF + kk;
    const float* Bsrc;
    float s = 1.0f;
    if (!nIm) { if (!kHi) { Bsrc = wre; } else { Bsrc = wim; s = -1.0f; } }
    else      { Bsrc = kHi ? wre : wim; }
    Bsrc += (size_t)nbase * INF + kk;

    float4 av[4], bv[4];
#pragma unroll
    for (int i = 0; i < 4; ++i) {
      av[i] = *reinterpret_cast<const float4*>(Asrc + (size_t)(srow + i * 32) * INF + scol);
      bv[i] = *reinterpret_cast<const float4*>(Bsrc + (size_t)(srow + i * 32) * INF + scol);
    }
    __syncthreads();
#pragma unroll
    for (int i = 0; i < 4; ++i) {
      bf16x4 a4, b4;
      a4[0] = (bf16_t)av[i].x; a4[1] = (bf16_t)av[i].y;
      a4[2] = (bf16_t)av[i].z; a4[3] = (bf16_t)av[i].w;
      b4[0] = (bf16_t)(bv[i].x * s); b4[1] = (bf16_t)(bv[i].y * s);
      b4[2] = (bf16_t)(bv[i].z * s); b4[3] = (bf16_t)(bv[i].w * s);
      *reinterpret_cast<bf16x4*>(&As[(srow + i * 32) * 40 + scol]) = a4;
      *reinterpret_cast<bf16x4*>(&Bs[(srow + i * 32) * 40 + scol]) = b4;
    }
    __syncthreads();

    bf16x8 a[4], b[4];
#pragma unroll
    for (int m = 0; m < 4; ++m)
      a[m] = *reinterpret_cast<const bf16x8*>(&As[(wm + m * 16 + lr) * 40 + lk]);
#pragma unroll
    for (int n = 0; n < 4; ++n)
      b[n] = *reinterpret_cast<const bf16x8*>(&Bs[(wn + n * 16 + lr) * 40 + lk]);
#pragma unroll
    for (int m = 0; m < 4; ++m)
#pragma unroll
      for (int n = 0; n < 4; ++n)
        acc[m][n] = __builtin_amdgcn_mfma_f32_16x16x32_bf16(a[m], b[n], acc[m][n], 0, 0, 0);
  }
  __syncthreads();

  const size_t imOff = (size_t)M_DIM * OUTF;
  int fq = (lane >> 4) * 4;
#pragma unroll
  for (int m = 0; m < 4; ++m) {
    int gr = bm * 128 + wm + m * 16 + fq;
#pragma unroll
    for (int n = 0; n < 4; ++n) {
      int gc = bn * 128 + wn + n * 16 + lr;
      float* dst = (gc < OUTF) ? (out + (size_t)gr * OUTF + gc)
                               : (out + imOff + (size_t)gr * OUTF + (gc - OUTF));
#pragma unroll
      for (int j = 0; j < 4; ++j)
        dst[(size_t)j * OUTF] = acc[m][n][j];
    }
  }
}

// ---------------------------------------------------------------------------
extern "C" void kernel_launch(void* const* d_in, const int* in_sizes, int n_in,
                              void* d_out, int out_size, void* d_ws, size_t ws_size,
                              hipStream_t stream) {
  const float* xre = (const float*)d_in[0];
  const float* xim = (const float*)d_in[1];
  const float* wre = (const float*)d_in[2];
  const float* wim = (const float*)d_in[3];
  float* out = (float*)d_out;

  const size_t need = (size_t)2 * 4096 * 4096 * sizeof(bf16_t);  // 64 MiB
  if (ws_size >= need) {
    bf16_t* Abf = (bf16_t*)d_ws;
    bf16_t* Bbf = Abf + (size_t)4096 * 4096;
    hipLaunchKernelGGL(pack_ab, dim3(16384), dim3(256), 0, stream,
                       xre, xim, wre, wim, Abf, Bbf);
    hipLaunchKernelGGL(gemm256, dim3(256), dim3(512), 0, stream,
                       Abf, Bbf, out);
  } else {
    hipLaunchKernelGGL(gemm_fused, dim3(1024), dim3(256), 0, stream,
                       xre, xim, wre, wim, out);
  }
}

// Round 3
// 143.264 us; speedup vs baseline: 1.5951x; 1.0440x over previous
//
#include <hip/hip_runtime.h>

typedef __bf16 bf16_t;
typedef __bf16 bf16x8 __attribute__((ext_vector_type(8)));
typedef __bf16 bf16x4 __attribute__((ext_vector_type(4)));
typedef float f32x4 __attribute__((ext_vector_type(4)));

#define M_DIM 4096
#define N_DIM 4096   // 2 * OUT_FEATURES
#define K_DIM 4096   // 2 * IN_FEATURES
#define OUTF 2048
#define INF 2048
#define LDK 4096
#define NT 64        // K-tiles of 64

// ---------------------------------------------------------------------------
// Pack kernel: build bf16 A = [x_re | x_im]  (4096 x 4096)
//              and  bf16 B = [[w_re, -w_im]; [w_im, w_re]] (4096 x 4096)
// ---------------------------------------------------------------------------
__global__ __launch_bounds__(256) void pack_ab(
    const float* __restrict__ xre, const float* __restrict__ xim,
    const float* __restrict__ wre, const float* __restrict__ wim,
    bf16_t* __restrict__ Abf, bf16_t* __restrict__ Bbf)
{
  size_t gid = (size_t)blockIdx.x * 256 + threadIdx.x;
  size_t e8  = gid * 8;
  const size_t MAT = (size_t)4096 * 4096;
  bool isB = e8 >= MAT;
  size_t e = isB ? (e8 - MAT) : e8;
  int row = (int)(e >> 12);
  int k   = (int)(e & 4095);

  const float* src;
  float s = 1.0f;
  if (!isB) {
    src = (k < INF) ? (xre + (size_t)row * INF + k)
                    : (xim + (size_t)row * INF + (k - INF));
  } else {
    if (row < OUTF) {
      if (k < INF) { src = wre + (size_t)row * INF + k; }
      else         { src = wim + (size_t)row * INF + (k - INF); s = -1.0f; }
    } else {
      int o = row - OUTF;
      src = (k < INF) ? (wim + (size_t)o * INF + k)
                      : (wre + (size_t)o * INF + (k - INF));
    }
  }
  const float4* p = reinterpret_cast<const float4*>(src);
  float4 f0 = p[0];
  float4 f1 = p[1];
  bf16x8 v;
  v[0] = (bf16_t)(f0.x * s); v[1] = (bf16_t)(f0.y * s);
  v[2] = (bf16_t)(f0.z * s); v[3] = (bf16_t)(f0.w * s);
  v[4] = (bf16_t)(f1.x * s); v[5] = (bf16_t)(f1.y * s);
  v[6] = (bf16_t)(f1.z * s); v[7] = (bf16_t)(f1.w * s);
  bf16_t* dst = (isB ? Bbf : Abf) + e;
  *reinterpret_cast<bf16x8*>(dst) = v;
}

// ---------------------------------------------------------------------------
__device__ __forceinline__ void gld_lds16(const void* g, void* l) {
  __builtin_amdgcn_global_load_lds(
      (const __attribute__((address_space(1))) void*)g,
      (__attribute__((address_space(3))) void*)l,
      16, 0, 0);
}

// ---------------------------------------------------------------------------
// 256x256 8-phase GEMM.  8 waves = 512 thr (2M x 4N), per-wave 128x64 out,
// BK=64, LDS 128 KiB double-buffered.
//
// LDS swizzle (derived for row-stride=128B layout, R2 post-mortem):
//   bank = (addr mod 128)/4, so spread must come from kbyte bits 4..6.
//   phys_kbyte = logical_kbyte XOR ((row&3)<<4) XOR (((row>>2)&1)<<6)
//   -> every quadrant ds_read_b128 covers all 8 16B-slots with exactly
//      8 lanes each (the 8-access/bank floor). Involution; applied on the
//      pre-swizzled global staging SOURCE + swizzled ds_read (rule 21).
// Counted vmcnt(2) at phase 4 only (1 half-tile in flight across boundary).
// ---------------------------------------------------------------------------

template<int QM, int QN>
__device__ __forceinline__ void mfma_quad(f32x4 (&acc)[8][4],
                                          const bf16x8 (&aF)[4][2],
                                          const bf16x8 (&bF)[2][2]) {
  __builtin_amdgcn_s_setprio(1);
#pragma unroll
  for (int m = 0; m < 4; ++m)
#pragma unroll
    for (int n = 0; n < 2; ++n) {
      f32x4 v = acc[QM * 4 + m][QN * 2 + n];
      v = __builtin_amdgcn_mfma_f32_16x16x32_bf16(aF[m][0], bF[n][0], v, 0, 0, 0);
      v = __builtin_amdgcn_mfma_f32_16x16x32_bf16(aF[m][1], bF[n][1], v, 0, 0, 0);
      acc[QM * 4 + m][QN * 2 + n] = v;
    }
  __builtin_amdgcn_s_setprio(0);
}

__global__ __launch_bounds__(512, 2) void gemm256(
    const bf16_t* __restrict__ A, const bf16_t* __restrict__ B,
    float* __restrict__ out)
{
  // LDS: buf c at c*65536 B; within buf: A-half0|A-half1|B-half0|B-half1,
  // each half = 128 rows x 64 cols bf16 = 16384 B (row stride 128 B).
  __shared__ alignas(16) bf16_t lds[2 * 32768];
  char* Lb = (char*)lds;

  const int tid  = threadIdx.x;
  const int lane = tid & 63;
  const int wid  = tid >> 6;
  const int wm   = wid >> 2;   // 0..1  -> rows wm*128..+127  (A-half wm)
  const int wn   = wid & 3;    // 0..3  -> cols wn*64..+63
  const int lr   = lane & 15;
  const int kg   = (lane >> 4) * 16;                         // logical slot
  const int xm   = ((lr & 3) << 4) | (((lr >> 2) & 1) << 6); // row-XOR mask

  int bid = blockIdx.x;
  int swz = (bid & 7) * 32 + (bid >> 3);   // XCD-aware, 256 blocks % 8 == 0
  const int bm = swz >> 4;                  // 0..15
  const int bn = swz & 15;                  // 0..15

  // Staging source precompute: physical P = j*8192 + tid*16 within a half;
  // row = P>>7, p = P&127; logical kbyte = p ^ ((row&3)<<4) ^ ((row>>2&1)<<6)
  int rS[2], kS[2];
#pragma unroll
  for (int j = 0; j < 2; ++j) {
    int P   = j * 8192 + tid * 16;
    int row = P >> 7;
    int p   = P & 127;
    int L   = p ^ ((row & 3) << 4) ^ (((row >> 2) & 1) << 6);
    rS[j] = row;
    kS[j] = L >> 1;           // k element (0..63)
  }
  const bf16_t* As0 = A + (size_t)(bm * 256 + rS[0]) * LDK + kS[0];
  const bf16_t* As1 = A + (size_t)(bm * 256 + rS[1]) * LDK + kS[1];
  const bf16_t* Bs0 = B + (size_t)(bn * 256 + rS[0]) * LDK + kS[0];
  const bf16_t* Bs1 = B + (size_t)(bn * 256 + rS[1]) * LDK + kS[1];
  const int dst16 = tid * 16;

#define STAGE_A(t, h, c) do {                                                  \
    gld_lds16(As0 + (size_t)(h) * 128 * LDK + (t) * 64,                        \
              Lb + (c) * 65536 + (h) * 16384 + dst16);                         \
    gld_lds16(As1 + (size_t)(h) * 128 * LDK + (t) * 64,                        \
              Lb + (c) * 65536 + (h) * 16384 + 8192 + dst16);                  \
  } while (0)
#define STAGE_B(t, h, c) do {                                                  \
    gld_lds16(Bs0 + (size_t)(h) * 128 * LDK + (t) * 64,                        \
              Lb + (c) * 65536 + 32768 + (h) * 16384 + dst16);                 \
    gld_lds16(Bs1 + (size_t)(h) * 128 * LDK + (t) * 64,                        \
              Lb + (c) * 65536 + 32768 + (h) * 16384 + 8192 + dst16);          \
  } while (0)
// A frag: row-in-half = qm*64+m*16+lr (half = wm); swizzled kbyte
#define RD_A(c, qm, m, ks)                                                     \
  (*(const bf16x8*)(Lb + (c) * 65536 + wm * 16384 +                            \
                    ((qm) * 64 + (m) * 16 + lr) * 128 +                        \
                    ((((ks) * 64) | kg) ^ xm)))
// B frag: row = wn*64+qn*32+n*16+lr -> half wn>>1, row-in-half rest
#define RD_B(c, qn, n, ks)                                                     \
  (*(const bf16x8*)(Lb + (c) * 65536 + 32768 + (wn >> 1) * 16384 +             \
                    ((wn & 1) * 64 + (qn) * 32 + (n) * 16 + lr) * 128 +        \
                    ((((ks) * 64) | kg) ^ xm)))
#define BAR()    __builtin_amdgcn_s_barrier()
#define LGKM0()  asm volatile("s_waitcnt lgkmcnt(0)" ::: "memory")

  f32x4 acc[8][4];
#pragma unroll
  for (int i = 0; i < 8; ++i)
#pragma unroll
    for (int j = 0; j < 4; ++j)
      acc[i][j] = (f32x4){0.f, 0.f, 0.f, 0.f};

  // Prologue: tile0 fully into buf0; tile1's A-half0 into buf1 (1 HT in flight)
  STAGE_A(0, 0, 0); STAGE_A(0, 1, 0);
  STAGE_B(0, 0, 0); STAGE_B(0, 1, 0);
  STAGE_A(1, 0, 1);
  asm volatile("s_waitcnt vmcnt(2)" ::: "memory");
  BAR();

  for (int t = 0; t < NT; ++t) {
    const int c = t & 1;
    bf16x8 aF[4][2], bF0[2][2], bF1[2][2];

    // ---- P1: quadrant (0,0). reads: A qm0 (8), B qn0 (4). stage t+1 A1.
#pragma unroll
    for (int m = 0; m < 4; ++m) {
      aF[m][0] = RD_A(c, 0, m, 0);
      aF[m][1] = RD_A(c, 0, m, 1);
    }
#pragma unroll
    for (int n = 0; n < 2; ++n) {
      bF0[n][0] = RD_B(c, 0, n, 0);
      bF0[n][1] = RD_B(c, 0, n, 1);
    }
    if (t + 1 < NT) STAGE_A(t + 1, 1, c ^ 1);
    BAR(); LGKM0();
    mfma_quad<0, 0>(acc, aF, bF0);
    BAR();

    // ---- P2: quadrant (0,1). reads: B qn1 (4). stage t+1 B0.
#pragma unroll
    for (int n = 0; n < 2; ++n) {
      bF1[n][0] = RD_B(c, 1, n, 0);
      bF1[n][1] = RD_B(c, 1, n, 1);
    }
    if (t + 1 < NT) STAGE_B(t + 1, 0, c ^ 1);
    BAR(); LGKM0();
    mfma_quad<0, 1>(acc, aF, bF1);
    BAR();

    // ---- P3: quadrant (1,1). reads: A qm1 (8). stage t+1 B1.
#pragma unroll
    for (int m = 0; m < 4; ++m) {
      aF[m][0] = RD_A(c, 1, m, 0);
      aF[m][1] = RD_A(c, 1, m, 1);
    }
    if (t + 1 < NT) STAGE_B(t + 1, 1, c ^ 1);
    BAR(); LGKM0();
    mfma_quad<1, 1>(acc, aF, bF1);
    BAR();

    // ---- P4: quadrant (1,0). no reads. stage t+2 A0 into buf c (safe: all
    // reads of buf c completed by P3's lgkmcnt+barrier). counted vmcnt.
    if (t + 2 < NT) STAGE_A(t + 2, 0, c);
    mfma_quad<1, 0>(acc, aF, bF0);
    if (t + 2 < NT) {
      asm volatile("s_waitcnt vmcnt(2)" ::: "memory");
    } else if (t + 1 < NT) {
      asm volatile("s_waitcnt vmcnt(0)" ::: "memory");
    }
    BAR();
  }

  // Epilogue: C/D layout col=lane&15, row=(lane>>4)*4+j (verified m89/m91)
  const size_t imOff = (size_t)M_DIM * OUTF;
  const int fq = (lane >> 4) * 4;
  const bool isIm = (bn * 256) >= OUTF;          // bn>=8 -> imaginary half
  float* obase = out + (isIm ? imOff : 0);
  const int colBase = bn * 256 - (isIm ? OUTF : 0) + wn * 64;
#pragma unroll
  for (int ar = 0; ar < 8; ++ar) {
    int gr = bm * 256 + wm * 128 + ar * 16 + fq;
#pragma unroll
    for (int cc = 0; cc < 4; ++cc) {
      int gc = colBase + cc * 16 + lr;
#pragma unroll
      for (int j = 0; j < 4; ++j)
        obase[(size_t)(gr + j) * OUTF + gc] = acc[ar][cc][j];
    }
  }
#undef STAGE_A
#undef STAGE_B
#undef RD_A
#undef RD_B
#undef BAR
#undef LGKM0
}

// ---------------------------------------------------------------------------
// Fallback: fused fp32->bf16 conversion + GEMM (no workspace needed).
// ---------------------------------------------------------------------------
__global__ __launch_bounds__(256) void gemm_fused(
    const float* __restrict__ xre, const float* __restrict__ xim,
    const float* __restrict__ wre, const float* __restrict__ wim,
    float* __restrict__ out)
{
  __shared__ alignas(16) bf16_t As[128 * 40];
  __shared__ alignas(16) bf16_t Bs[128 * 40];

  int tid = threadIdx.x;
  int bid = blockIdx.x;
  int swz = (bid & 7) * 128 + (bid >> 3);
  int bm = swz >> 5;
  int bn = swz & 31;

  int lane = tid & 63;
  int w    = tid >> 6;
  int wm   = (w >> 1) * 64;
  int wn   = (w & 1) * 64;
  int lr   = lane & 15;
  int lk   = (lane >> 4) * 8;

  f32x4 acc[4][4];
#pragma unroll
  for (int m = 0; m < 4; ++m)
#pragma unroll
    for (int n = 0; n < 4; ++n)
      acc[m][n] = (f32x4){0.f, 0.f, 0.f, 0.f};

  int srow = tid >> 3;
  int scol = (tid & 7) * 4;

  bool nIm  = (bn * 128) >= OUTF;
  int nbase = nIm ? (bn * 128 - OUTF) : (bn * 128);

  for (int kt = 0; kt < K_DIM / 32; ++kt) {
    int k0 = kt * 32;
    bool kHi = (k0 >= INF);
    int kk = kHi ? (k0 - INF) : k0;

    const float* Asrc = (kHi ? xim : xre) + (size_t)(bm * 128) * INF + kk;
    const float* Bsrc;
    float s = 1.0f;
    if (!nIm) { if (!kHi) { Bsrc = wre; } else { Bsrc = wim; s = -1.0f; } }
    else      { Bsrc = kHi ? wre : wim; }
    Bsrc += (size_t)nbase * INF + kk;

    float4 av[4], bv[4];
#pragma unroll
    for (int i = 0; i < 4; ++i) {
      av[i] = *reinterpret_cast<const float4*>(Asrc + (size_t)(srow + i * 32) * INF + scol);
      bv[i] = *reinterpret_cast<const float4*>(Bsrc + (size_t)(srow + i * 32) * INF + scol);
    }
    __syncthreads();
#pragma unroll
    for (int i = 0; i < 4; ++i) {
      bf16x4 a4, b4;
      a4[0] = (bf16_t)av[i].x; a4[1] = (bf16_t)av[i].y;
      a4[2] = (bf16_t)av[i].z; a4[3] = (bf16_t)av[i].w;
      b4[0] = (bf16_t)(bv[i].x * s); b4[1] = (bf16_t)(bv[i].y * s);
      b4[2] = (bf16_t)(bv[i].z * s); b4[3] = (bf16_t)(bv[i].w * s);
      *reinterpret_cast<bf16x4*>(&As[(srow + i * 32) * 40 + scol]) = a4;
      *reinterpret_cast<bf16x4*>(&Bs[(srow + i * 32) * 40 + scol]) = b4;
    }
    __syncthreads();

    bf16x8 a[4], b[4];
#pragma unroll
    for (int m = 0; m < 4; ++m)
      a[m] = *reinterpret_cast<const bf16x8*>(&As[(wm + m * 16 + lr) * 40 + lk]);
#pragma unroll
    for (int n = 0; n < 4; ++n)
      b[n] = *reinterpret_cast<const bf16x8*>(&Bs[(wn + n * 16 + lr) * 40 + lk]);
#pragma unroll
    for (int m = 0; m < 4; ++m)
#pragma unroll
      for (int n = 0; n < 4; ++n)
        acc[m][n] = __builtin_amdgcn_mfma_f32_16x16x32_bf16(a[m], b[n], acc[m][n], 0, 0, 0);
  }
  __syncthreads();

  const size_t imOff = (size_t)M_DIM * OUTF;
  int fq = (lane >> 4) * 4;
#pragma unroll
  for (int m = 0; m < 4; ++m) {
    int gr = bm * 128 + wm + m * 16 + fq;
#pragma unroll
    for (int n = 0; n < 4; ++n) {
      int gc = bn * 128 + wn + n * 16 + lr;
      float* dst = (gc < OUTF) ? (out + (size_t)gr * OUTF + gc)
                               : (out + imOff + (size_t)gr * OUTF + (gc - OUTF));
#pragma unroll
      for (int j = 0; j < 4; ++j)
        dst[(size_t)j * OUTF] = acc[m][n][j];
    }
  }
}

// ---------------------------------------------------------------------------
extern "C" void kernel_launch(void* const* d_in, const int* in_sizes, int n_in,
                              void* d_out, int out_size, void* d_ws, size_t ws_size,
                              hipStream_t stream) {
  const float* xre = (const float*)d_in[0];
  const float* xim = (const float*)d_in[1];
  const float* wre = (const float*)d_in[2];
  const float* wim = (const float*)d_in[3];
  float* out = (float*)d_out;

  const size_t need = (size_t)2 * 4096 * 4096 * sizeof(bf16_t);  // 64 MiB
  if (ws_size >= need) {
    bf16_t* Abf = (bf16_t*)d_ws;
    bf16_t* Bbf = Abf + (size_t)4096 * 4096;
    hipLaunchKernelGGL(pack_ab, dim3(16384), dim3(256), 0, stream,
                       xre, xim, wre, wim, Abf, Bbf);
    hipLaunchKernelGGL(gemm256, dim3(256), dim3(512), 0, stream,
                       Abf, Bbf, out);
  } else {
    hipLaunchKernelGGL(gemm_fused, dim3(1024), dim3(256), 0, stream,
                       xre, xim, wre, wim, out);
  }
}